// Round 1
// baseline (1779.203 us; speedup 1.0000x reference)
//
#include <hip/hip_runtime.h>
#include <hip/hip_bf16.h>
#include <cstdint>
#include <cstddef>

#define DD 512
#define D4 128   // DD/4

// ---------------- CSR build ----------------

__global__ void hist_kernel(const int* __restrict__ dg, const int* __restrict__ df,
                            int* __restrict__ deg_g, int* __restrict__ deg_f, int E) {
  int i = blockIdx.x * blockDim.x + threadIdx.x;
  int total = 2 * E;
  int stride = gridDim.x * blockDim.x;
  for (; i < total; i += stride) {
    if (i < E) atomicAdd(&deg_g[dg[i]], 1);
    else       atomicAdd(&deg_f[df[i - E]], 1);
  }
}

__global__ void scan_kernel(const int* __restrict__ deg_g, const int* __restrict__ deg_f,
                            int* __restrict__ rp_g, int* __restrict__ rp_f,
                            int* __restrict__ cur_g, int* __restrict__ cur_f, int N) {
  const int* deg = (blockIdx.x == 0) ? deg_g : deg_f;
  int* rp  = (blockIdx.x == 0) ? rp_g  : rp_f;
  int* cur = (blockIdx.x == 0) ? cur_g : cur_f;
  __shared__ int sums[256];
  int t = threadIdx.x;
  int strip = (N + 255) / 256;
  int base = t * strip;
  int lim = N - base; if (lim > strip) lim = strip; if (lim < 0) lim = 0;
  int s = 0;
  for (int j = 0; j < lim; ++j) s += deg[base + j];
  sums[t] = s;
  __syncthreads();
  // inclusive Hillis-Steele scan over 256 strip sums
  for (int off = 1; off < 256; off <<= 1) {
    int v = sums[t];
    int add = (t >= off) ? sums[t - off] : 0;
    __syncthreads();
    sums[t] = v + add;
    __syncthreads();
  }
  int run = (t == 0) ? 0 : sums[t - 1];
  for (int j = 0; j < lim; ++j) {
    rp[base + j] = run;
    cur[base + j] = run;
    run += deg[base + j];
  }
  if (t == 255) rp[N] = sums[255];
}

__global__ void fill_kernel(const int* __restrict__ src, const int* __restrict__ dst,
                            int* __restrict__ cur, int* __restrict__ csr, int E) {
  int i = blockIdx.x * blockDim.x + threadIdx.x;
  int stride = gridDim.x * blockDim.x;
  for (; i < E; i += stride) {
    int d = dst[i];
    int pos = atomicAdd(&cur[d], 1);
    csr[pos] = src[i];
  }
}

// ---------------- per-dst gather (segment_sum, no float atomics) ----------------
// X[i,:] = norm[i] * sum_{e in edges(dst=i)} norm[src_e] * feat[src_e,:]

__global__ __launch_bounds__(128) void gather_kernel(const float* __restrict__ feat,
    const float* __restrict__ norm, const int* __restrict__ rp, const int* __restrict__ csr,
    float* __restrict__ X, int N) {
  int i = blockIdx.x;
  if (i >= N) return;
  int c = threadIdx.x;  // float4 lane: col = 4*c
  const float4* f4 = (const float4*)feat;
  float4 acc = make_float4(0.f, 0.f, 0.f, 0.f);
  int b = rp[i], e = rp[i + 1];
  for (int j = b; j < e; ++j) {
    int s = csr[j];
    float gs = norm[s];
    float4 v = f4[(size_t)s * D4 + c];
    acc.x += gs * v.x; acc.y += gs * v.y; acc.z += gs * v.z; acc.w += gs * v.w;
  }
  float gi = norm[i];
  float4 o = make_float4(acc.x * gi, acc.y * gi, acc.z * gi, acc.w * gi);
  ((float4*)X)[(size_t)i * D4 + c] = o;
}

// ---------------- fused 3-source GEMM + bias + relu ----------------
// out = relu(Xh@Wh + Xs@Ws + M@Wm + (bh+bs+bm)), all [N,512] row-major.

#define GBM 128
#define GBN 128
#define GBK 16

__global__ __launch_bounds__(256) void gemm3_kernel(
    const float* __restrict__ Xh, const float* __restrict__ Xs, const float* __restrict__ Mm,
    const float* __restrict__ Wh, const float* __restrict__ Wsp, const float* __restrict__ Wm,
    const float* __restrict__ bh, const float* __restrict__ bs, const float* __restrict__ bm,
    float* __restrict__ out, int Mrows) {
  __shared__ float As[GBK][GBM + 4];  // row stride 132 floats = 528B (16B aligned)
  __shared__ float Bs[GBK][GBN + 4];
  int tid = threadIdx.x;
  int tx = tid & 15;   // n direction
  int ty = tid >> 4;   // m direction
  int bn0 = blockIdx.x * GBN;
  int bm0 = blockIdx.y * GBM;

  float acc[8][8];
#pragma unroll
  for (int i = 0; i < 8; ++i)
#pragma unroll
    for (int j = 0; j < 8; ++j) acc[i][j] = 0.f;

  const float* Aarr[3] = {Xh, Xs, Mm};
  const float* Warr[3] = {Wh, Wsp, Wm};

  for (int si = 0; si < 3; ++si) {
    const float* A = Aarr[si];
    const float* W = Warr[si];
    for (int k0 = 0; k0 < DD; k0 += GBK) {
      // A tile: GBM x GBK = 2048 floats = 512 float4; 2 per thread; store transposed
#pragma unroll
      for (int l = 0; l < 2; ++l) {
        int idx = tid + (l << 8);
        int r = idx >> 2;
        int kk = (idx & 3) << 2;
        int gr = bm0 + r;
        float4 v = make_float4(0.f, 0.f, 0.f, 0.f);
        if (gr < Mrows) v = *(const float4*)(A + (size_t)gr * DD + k0 + kk);
        As[kk + 0][r] = v.x; As[kk + 1][r] = v.y; As[kk + 2][r] = v.z; As[kk + 3][r] = v.w;
      }
      // B tile: GBK x GBN = 2048 floats; 2 float4 per thread, row-major
#pragma unroll
      for (int l = 0; l < 2; ++l) {
        int idx = tid + (l << 8);
        int r = idx >> 5;
        int nn = (idx & 31) << 2;
        float4 v = *(const float4*)(W + (size_t)(k0 + r) * DD + bn0 + nn);
        *(float4*)(&Bs[r][nn]) = v;
      }
      __syncthreads();
#pragma unroll
      for (int k = 0; k < GBK; ++k) {
        float a[8], b[8];
        *(float4*)(a)     = *(const float4*)(&As[k][ty * 8]);
        *(float4*)(a + 4) = *(const float4*)(&As[k][ty * 8 + 4]);
        *(float4*)(b)     = *(const float4*)(&Bs[k][tx * 8]);
        *(float4*)(b + 4) = *(const float4*)(&Bs[k][tx * 8 + 4]);
#pragma unroll
        for (int mi = 0; mi < 8; ++mi)
#pragma unroll
          for (int ni = 0; ni < 8; ++ni) acc[mi][ni] += a[mi] * b[ni];
      }
      __syncthreads();
    }
  }

  // epilogue: bias + relu
#pragma unroll
  for (int mi = 0; mi < 8; ++mi) {
    int gr = bm0 + ty * 8 + mi;
    if (gr < Mrows) {
      size_t rowoff = (size_t)gr * DD;
#pragma unroll
      for (int ni = 0; ni < 8; ni += 4) {
        int col = bn0 + tx * 8 + ni;
        float4 o;
        o.x = acc[mi][ni + 0] + bh[col + 0] + bs[col + 0] + bm[col + 0];
        o.y = acc[mi][ni + 1] + bh[col + 1] + bs[col + 1] + bm[col + 1];
        o.z = acc[mi][ni + 2] + bh[col + 2] + bs[col + 2] + bm[col + 2];
        o.w = acc[mi][ni + 3] + bh[col + 3] + bs[col + 3] + bm[col + 3];
        o.x = o.x > 0.f ? o.x : 0.f;
        o.y = o.y > 0.f ? o.y : 0.f;
        o.z = o.z > 0.f ? o.z : 0.f;
        o.w = o.w > 0.f ? o.w : 0.f;
        *(float4*)(out + rowoff + col) = o;
      }
    }
  }
}

// ---------------- launcher ----------------

extern "C" void kernel_launch(void* const* d_in, const int* in_sizes, int n_in,
                              void* d_out, int out_size, void* d_ws, size_t ws_size,
                              hipStream_t stream) {
  const float* h   = (const float*)d_in[0];
  const float* s   = (const float*)d_in[1];
  const float* m   = (const float*)d_in[2];
  const float* ng  = (const float*)d_in[3];
  const float* nf  = (const float*)d_in[4];
  const int* src_g = (const int*)d_in[5];
  const int* dst_g = (const int*)d_in[6];
  const int* src_f = (const int*)d_in[7];
  const int* dst_f = (const int*)d_in[8];
  const float* wh  = (const float*)d_in[9];
  const float* wsp = (const float*)d_in[10];
  const float* wm  = (const float*)d_in[11];
  const float* bh  = (const float*)d_in[12];
  const float* bs  = (const float*)d_in[13];
  const float* bm  = (const float*)d_in[14];
  float* out = (float*)d_out;

  int N = in_sizes[3];   // norm_g has N elements
  int E = in_sizes[5];   // src_g has E elements

  // workspace layout
  float* Xh = (float*)d_ws;
  float* Xs = Xh + (size_t)N * DD;
  int* deg_g = (int*)(Xs + (size_t)N * DD);
  int* deg_f = deg_g + N;
  int* rp_g  = deg_f + N;
  int* rp_f  = rp_g + (N + 1);
  int* cur_g = rp_f + (N + 1);
  int* cur_f = cur_g + N;
  int* csr_g = cur_f + N;
  int* csr_f = csr_g + E;

  hipMemsetAsync(deg_g, 0, 2 * (size_t)N * sizeof(int), stream);
  hist_kernel<<<2048, 256, 0, stream>>>(dst_g, dst_f, deg_g, deg_f, E);
  scan_kernel<<<2, 256, 0, stream>>>(deg_g, deg_f, rp_g, rp_f, cur_g, cur_f, N);
  fill_kernel<<<2048, 256, 0, stream>>>(src_g, dst_g, cur_g, csr_g, E);
  fill_kernel<<<2048, 256, 0, stream>>>(src_f, dst_f, cur_f, csr_f, E);
  gather_kernel<<<N, 128, 0, stream>>>(h, ng, rp_g, csr_g, Xh, N);
  gather_kernel<<<N, 128, 0, stream>>>(s, nf, rp_f, csr_f, Xs, N);

  dim3 gg(DD / GBN, (N + GBM - 1) / GBM);
  gemm3_kernel<<<gg, 256, 0, stream>>>(Xh, Xs, m, wh, wsp, wm, bh, bs, bm, out, N);
}

// Round 3
// 1169.737 us; speedup vs baseline: 1.5210x; 1.5210x over previous
//
#include <hip/hip_runtime.h>
#include <hip/hip_bf16.h>
#include <cstdint>
#include <cstddef>

#define DD 512
#define D4 128

typedef unsigned short u16;
typedef unsigned int u32;
typedef short s8v __attribute__((ext_vector_type(8)));
typedef float f4v __attribute__((ext_vector_type(4)));

__device__ __forceinline__ u16 f2bf(float f) {
  u32 u = __builtin_bit_cast(u32, f);
  u = (u + 0x7FFFu + ((u >> 16) & 1u)) >> 16;  // RNE
  return (u16)u;
}
__device__ __forceinline__ float bf2f(u16 h) {
  u32 u = ((u32)h) << 16;
  return __builtin_bit_cast(float, u);
}

__device__ __forceinline__ void glds16(const void* g, void* l) {
  __builtin_amdgcn_global_load_lds(
      (const __attribute__((address_space(1))) void*)g,
      (__attribute__((address_space(3))) void*)l, 16, 0, 0);
}

// ---------------- CSR build ----------------

__global__ void hist_kernel(const int* __restrict__ dg, const int* __restrict__ df,
                            int* __restrict__ deg_g, int* __restrict__ deg_f, int E) {
  int i = blockIdx.x * blockDim.x + threadIdx.x;
  int total = 2 * E;
  int stride = gridDim.x * blockDim.x;
  for (; i < total; i += stride) {
    if (i < E) atomicAdd(&deg_g[dg[i]], 1);
    else       atomicAdd(&deg_f[df[i - E]], 1);
  }
}

__global__ void scan_kernel(const int* __restrict__ deg_g, const int* __restrict__ deg_f,
                            int* __restrict__ rp_g, int* __restrict__ rp_f,
                            int* __restrict__ cur_g, int* __restrict__ cur_f, int N) {
  const int* deg = (blockIdx.x == 0) ? deg_g : deg_f;
  int* rp  = (blockIdx.x == 0) ? rp_g  : rp_f;
  int* cur = (blockIdx.x == 0) ? cur_g : cur_f;
  __shared__ int sums[256];
  int t = threadIdx.x;
  int strip = (N + 255) / 256;
  int base = t * strip;
  int lim = N - base; if (lim > strip) lim = strip; if (lim < 0) lim = 0;
  int s = 0;
  for (int j = 0; j < lim; ++j) s += deg[base + j];
  sums[t] = s;
  __syncthreads();
  for (int off = 1; off < 256; off <<= 1) {
    int v = sums[t];
    int add = (t >= off) ? sums[t - off] : 0;
    __syncthreads();
    sums[t] = v + add;
    __syncthreads();
  }
  int run = (t == 0) ? 0 : sums[t - 1];
  for (int j = 0; j < lim; ++j) {
    rp[base + j] = run;
    cur[base + j] = run;
    run += deg[base + j];
  }
  if (t == 255) rp[N] = sums[255];
}

__global__ void fill_kernel(const int* __restrict__ src, const int* __restrict__ dst,
                            int* __restrict__ cur, int* __restrict__ csr, int E) {
  int i = blockIdx.x * blockDim.x + threadIdx.x;
  int stride = gridDim.x * blockDim.x;
  for (; i < E; i += stride) {
    int d = dst[i];
    int pos = atomicAdd(&cur[d], 1);
    csr[pos] = src[i];
  }
}

// ---------------- per-dst gather (segment_sum, no float atomics) ----------------

__global__ __launch_bounds__(128) void gather_kernel(const float* __restrict__ feat,
    const float* __restrict__ norm, const int* __restrict__ rp, const int* __restrict__ csr,
    float* __restrict__ X, int N) {
  int i = blockIdx.x;
  if (i >= N) return;
  int c = threadIdx.x;
  const float4* f4 = (const float4*)feat;
  float4 acc = make_float4(0.f, 0.f, 0.f, 0.f);
  int b = rp[i], e = rp[i + 1];
  for (int j = b; j < e; ++j) {
    int s = csr[j];
    float gs = norm[s];
    float4 v = f4[(size_t)s * D4 + c];
    acc.x += gs * v.x; acc.y += gs * v.y; acc.z += gs * v.z; acc.w += gs * v.w;
  }
  float gi = norm[i];
  float4 o = make_float4(acc.x * gi, acc.y * gi, acc.z * gi, acc.w * gi);
  ((float4*)X)[(size_t)i * D4 + c] = o;
}

// ---------------- W transpose + bf16 hi/lo split: Wt[si][col][k] ----------------

__global__ __launch_bounds__(256) void wsplit_kernel(
    const float* __restrict__ wh, const float* __restrict__ ws, const float* __restrict__ wm,
    u16* __restrict__ WtHi, u16* __restrict__ WtLo) {
  __shared__ float tile[64][65];
  int si = blockIdx.y;
  const float* W = (si == 0) ? wh : (si == 1) ? ws : wm;
  int tb = blockIdx.x;       // 0..63
  int kb = (tb >> 3) << 6;
  int cb = (tb & 7) << 6;
  int t = threadIdx.x;
#pragma unroll
  for (int i = 0; i < 16; ++i) {
    int idx = t + (i << 8);
    int kr = idx >> 6, cc = idx & 63;
    tile[kr][cc] = W[(size_t)(kb + kr) * DD + cb + cc];
  }
  __syncthreads();
  size_t base = (size_t)si * DD * DD;
#pragma unroll
  for (int i = 0; i < 16; ++i) {
    int idx = t + (i << 8);
    int cr = idx >> 6, kk = idx & 63;
    float v = tile[kk][cr];
    u16 hi = f2bf(v);
    u16 lo = f2bf(v - bf2f(hi));
    size_t off = base + (size_t)(cb + cr) * DD + kb + kk;
    WtHi[off] = hi;
    WtLo[off] = lo;
  }
}

// ---------------- fused 3-source split-bf16 MFMA GEMM + bias + relu ----------------
// out = relu([Xh|Xs|M] @ [Wh;Ws;Wm] + (bh+bs+bm)), via Ah*Bh + Al*Bh + Ah*Bl.

#define BM 128
#define BN 256
#define BK 32

__global__ __launch_bounds__(256, 2) void gemm3_mfma(
    const float* __restrict__ Xh, const float* __restrict__ Xs, const float* __restrict__ Mm,
    const u16* __restrict__ WtHi, const u16* __restrict__ WtLo,
    const float* __restrict__ bh, const float* __restrict__ bs, const float* __restrict__ bm,
    float* __restrict__ out, int Mrows) {
  __shared__ u16 sAh[BM * BK];  // [row][k], 64B row stride
  __shared__ u16 sAl[BM * BK];
  __shared__ u16 sBh[BN * BK];  // [col][k]
  __shared__ u16 sBl[BN * BK];

  int tid = threadIdx.x;
  int wv = tid >> 6;
  int lane = tid & 63;
  int bm0 = blockIdx.y * BM;
  int bn0 = blockIdx.x * BN;

  f4v acc[8][4];
#pragma unroll
  for (int i = 0; i < 8; ++i)
#pragma unroll
    for (int j = 0; j < 4; ++j) acc[i][j] = (f4v){0.f, 0.f, 0.f, 0.f};

  const float* Aarr[3] = {Xh, Xs, Mm};

  for (int si = 0; si < 3; ++si) {
    const float* A = Aarr[si];
    const u16* WH = WtHi + (size_t)si * DD * DD;
    const u16* WL = WtLo + (size_t)si * DD * DD;
    for (int k0 = 0; k0 < DD; k0 += BK) {
      // --- B tile: async global->LDS, bf16 already split; 16 cols per instr ---
      {
        int colo = lane >> 2;   // 0..15
        int chunk = lane & 3;   // 16B chunk = 8 k
#pragma unroll
        for (int i = 0; i < 4; ++i) {
          int cg = wv * 4 + i;  // col-group of 16
          int col = cg * 16 + colo;
          const u16* gh = WH + (size_t)(bn0 + col) * DD + k0 + chunk * 8;
          const u16* gl = WL + (size_t)(bn0 + col) * DD + k0 + chunk * 8;
          glds16(gh, (char*)sBh + cg * 1024);
          glds16(gl, (char*)sBl + cg * 1024);
        }
      }
      // --- A tile: fp32 reg-stage, split to bf16 hi/lo, ds_write ---
      {
        float4 vv[4];
#pragma unroll
        for (int i = 0; i < 4; ++i) {
          int idx = tid + (i << 8);
          int row = idx >> 3;
          int gr = bm0 + row;
          int kc = idx & 7;
          vv[i] = make_float4(0.f, 0.f, 0.f, 0.f);
          if (gr < Mrows) vv[i] = *(const float4*)(A + (size_t)gr * DD + k0 + kc * 4);
        }
#pragma unroll
        for (int i = 0; i < 4; ++i) {
          int idx = tid + (i << 8);
          int row = idx >> 3;
          int kc = idx & 7;
          float4 v = vv[i];
          u16 h0 = f2bf(v.x), h1 = f2bf(v.y), h2 = f2bf(v.z), h3 = f2bf(v.w);
          u16 l0 = f2bf(v.x - bf2f(h0)), l1 = f2bf(v.y - bf2f(h1));
          u16 l2 = f2bf(v.z - bf2f(h2)), l3 = f2bf(v.w - bf2f(h3));
          uint2 ph = make_uint2((u32)h0 | ((u32)h1 << 16), (u32)h2 | ((u32)h3 << 16));
          uint2 pl = make_uint2((u32)l0 | ((u32)l1 << 16), (u32)l2 | ((u32)l3 << 16));
          *(uint2*)(sAh + row * BK + kc * 4) = ph;
          *(uint2*)(sAl + row * BK + kc * 4) = pl;
        }
      }
      __syncthreads();
      // --- fragments + MFMA ---
      int kchunk = (lane >> 4) * 8;
      int rr = lane & 15;
      s8v bhf[4], blf[4];
#pragma unroll
      for (int ng = 0; ng < 4; ++ng) {
        int col = wv * 64 + ng * 16 + rr;
        bhf[ng] = *(const s8v*)(sBh + col * BK + kchunk);
        blf[ng] = *(const s8v*)(sBl + col * BK + kchunk);
      }
#pragma unroll
      for (int mg = 0; mg < 8; ++mg) {
        int row = mg * 16 + rr;
        s8v ah = *(const s8v*)(sAh + row * BK + kchunk);
        s8v al = *(const s8v*)(sAl + row * BK + kchunk);
#pragma unroll
        for (int ng = 0; ng < 4; ++ng) {
          acc[mg][ng] = __builtin_amdgcn_mfma_f32_16x16x32_bf16(ah, bhf[ng], acc[mg][ng], 0, 0, 0);
          acc[mg][ng] = __builtin_amdgcn_mfma_f32_16x16x32_bf16(al, bhf[ng], acc[mg][ng], 0, 0, 0);
          acc[mg][ng] = __builtin_amdgcn_mfma_f32_16x16x32_bf16(ah, blf[ng], acc[mg][ng], 0, 0, 0);
        }
      }
      __syncthreads();
    }
  }

  // --- epilogue: bias + relu, C/D layout col=lane&15, row=(lane>>4)*4+reg ---
  int rr = lane & 15;
  int rgrp = lane >> 4;
  float bias[4];
#pragma unroll
  for (int ng = 0; ng < 4; ++ng) {
    int col = bn0 + wv * 64 + ng * 16 + rr;
    bias[ng] = bh[col] + bs[col] + bm[col];
  }
#pragma unroll
  for (int mg = 0; mg < 8; ++mg) {
#pragma unroll
    for (int r = 0; r < 4; ++r) {
      int row = bm0 + mg * 16 + rgrp * 4 + r;
      if (row < Mrows) {
#pragma unroll
        for (int ng = 0; ng < 4; ++ng) {
          int col = bn0 + wv * 64 + ng * 16 + rr;
          float v = acc[mg][ng][r] + bias[ng];
          out[(size_t)row * DD + col] = v > 0.f ? v : 0.f;
        }
      }
    }
  }
}

// ---------------- launcher ----------------

extern "C" void kernel_launch(void* const* d_in, const int* in_sizes, int n_in,
                              void* d_out, int out_size, void* d_ws, size_t ws_size,
                              hipStream_t stream) {
  const float* h   = (const float*)d_in[0];
  const float* s   = (const float*)d_in[1];
  const float* m   = (const float*)d_in[2];
  const float* ng  = (const float*)d_in[3];
  const float* nf  = (const float*)d_in[4];
  const int* src_g = (const int*)d_in[5];
  const int* dst_g = (const int*)d_in[6];
  const int* src_f = (const int*)d_in[7];
  const int* dst_f = (const int*)d_in[8];
  const float* wh  = (const float*)d_in[9];
  const float* wsp = (const float*)d_in[10];
  const float* wm  = (const float*)d_in[11];
  const float* bh  = (const float*)d_in[12];
  const float* bs  = (const float*)d_in[13];
  const float* bm  = (const float*)d_in[14];
  float* out = (float*)d_out;

  int N = in_sizes[3];
  int E = in_sizes[5];

  // workspace layout (16B-aligned segments)
  float* Xh = (float*)d_ws;
  float* Xs = Xh + (size_t)N * DD;
  u16* WtHi = (u16*)(Xs + (size_t)N * DD);
  u16* WtLo = WtHi + (size_t)3 * DD * DD;
  int* deg_g = (int*)(WtLo + (size_t)3 * DD * DD);
  int* deg_f = deg_g + N;
  int* rp_g  = deg_f + N;
  int* rp_f  = rp_g + (N + 1);
  int* cur_g = rp_f + (N + 1);
  int* cur_f = cur_g + N;
  int* csr_g = cur_f + N;
  int* csr_f = csr_g + E;

  hipMemsetAsync(deg_g, 0, 2 * (size_t)N * sizeof(int), stream);
  wsplit_kernel<<<dim3(64, 3), 256, 0, stream>>>(wh, wsp, wm, WtHi, WtLo);
  hist_kernel<<<2048, 256, 0, stream>>>(dst_g, dst_f, deg_g, deg_f, E);
  scan_kernel<<<2, 256, 0, stream>>>(deg_g, deg_f, rp_g, rp_f, cur_g, cur_f, N);
  fill_kernel<<<2048, 256, 0, stream>>>(src_g, dst_g, cur_g, csr_g, E);
  fill_kernel<<<2048, 256, 0, stream>>>(src_f, dst_f, cur_f, csr_f, E);
  gather_kernel<<<N, 128, 0, stream>>>(h, ng, rp_g, csr_g, Xh, N);
  gather_kernel<<<N, 128, 0, stream>>>(s, nf, rp_f, csr_f, Xs, N);

  dim3 gg(DD / BN, (N + BM - 1) / BM);
  gemm3_mfma<<<gg, 256, 0, stream>>>(Xh, Xs, m, WtHi, WtLo, bh, bs, bm, out, N);
}

// Round 4
// 1094.977 us; speedup vs baseline: 1.6249x; 1.0683x over previous
//
#include <hip/hip_runtime.h>
#include <hip/hip_bf16.h>
#include <cstdint>
#include <cstddef>

#define DD 512
#define D4 128

typedef unsigned short u16;
typedef unsigned int u32;
typedef short s8v __attribute__((ext_vector_type(8)));
typedef float f4v __attribute__((ext_vector_type(4)));

__device__ __forceinline__ u16 f2bf(float f) {
  u32 u = __builtin_bit_cast(u32, f);
  u = (u + 0x7FFFu + ((u >> 16) & 1u)) >> 16;  // RNE
  return (u16)u;
}
__device__ __forceinline__ float bf2f(u16 h) {
  u32 u = ((u32)h) << 16;
  return __builtin_bit_cast(float, u);
}

__device__ __forceinline__ void glds16(const void* g, void* l) {
  __builtin_amdgcn_global_load_lds(
      (const __attribute__((address_space(1))) void*)g,
      (__attribute__((address_space(3))) void*)l, 16, 0, 0);
}

// ---------------- CSR build ----------------

__global__ void hist_kernel(const int* __restrict__ dg, const int* __restrict__ df,
                            int* __restrict__ deg_g, int* __restrict__ deg_f, int E) {
  int i = blockIdx.x * blockDim.x + threadIdx.x;
  int total = 2 * E;
  int stride = gridDim.x * blockDim.x;
  for (; i < total; i += stride) {
    if (i < E) atomicAdd(&deg_g[dg[i]], 1);
    else       atomicAdd(&deg_f[df[i - E]], 1);
  }
}

__global__ void scan_kernel(const int* __restrict__ deg_g, const int* __restrict__ deg_f,
                            int* __restrict__ rp_g, int* __restrict__ rp_f,
                            int* __restrict__ cur_g, int* __restrict__ cur_f, int N) {
  const int* deg = (blockIdx.x == 0) ? deg_g : deg_f;
  int* rp  = (blockIdx.x == 0) ? rp_g  : rp_f;
  int* cur = (blockIdx.x == 0) ? cur_g : cur_f;
  __shared__ int sums[256];
  int t = threadIdx.x;
  int strip = (N + 255) / 256;
  int base = t * strip;
  int lim = N - base; if (lim > strip) lim = strip; if (lim < 0) lim = 0;
  int s = 0;
  for (int j = 0; j < lim; ++j) s += deg[base + j];
  sums[t] = s;
  __syncthreads();
  for (int off = 1; off < 256; off <<= 1) {
    int v = sums[t];
    int add = (t >= off) ? sums[t - off] : 0;
    __syncthreads();
    sums[t] = v + add;
    __syncthreads();
  }
  int run = (t == 0) ? 0 : sums[t - 1];
  for (int j = 0; j < lim; ++j) {
    rp[base + j] = run;
    cur[base + j] = run;
    run += deg[base + j];
  }
  if (t == 255) rp[N] = sums[255];
}

__global__ void fill_kernel(const int* __restrict__ src, const int* __restrict__ dst,
                            int* __restrict__ cur, int* __restrict__ csr, int E) {
  int i = blockIdx.x * blockDim.x + threadIdx.x;
  int stride = gridDim.x * blockDim.x;
  for (; i < E; i += stride) {
    int d = dst[i];
    int pos = atomicAdd(&cur[d], 1);
    csr[pos] = src[i];
  }
}

// ---------------- per-dst gather; writes pre-split bf16 hi/lo planes ----------------
// X[i,:] = norm[i] * sum_{e: dst=i} norm[src_e] * feat[src_e,:]

__global__ __launch_bounds__(128) void gather_kernel(const float* __restrict__ feat,
    const float* __restrict__ norm, const int* __restrict__ rp, const int* __restrict__ csr,
    u16* __restrict__ XHi, u16* __restrict__ XLo, int N) {
  int i = blockIdx.x;
  if (i >= N) return;
  int c = threadIdx.x;  // float4 lane: cols 4c..4c+3
  const float4* f4 = (const float4*)feat;
  float4 acc = make_float4(0.f, 0.f, 0.f, 0.f);
  int b = rp[i], e = rp[i + 1];
  int j = b;
  for (; j + 4 <= e; j += 4) {
    int s0 = csr[j], s1 = csr[j + 1], s2 = csr[j + 2], s3 = csr[j + 3];
    float g0 = norm[s0], g1 = norm[s1], g2 = norm[s2], g3 = norm[s3];
    float4 v0 = f4[(size_t)s0 * D4 + c];
    float4 v1 = f4[(size_t)s1 * D4 + c];
    float4 v2 = f4[(size_t)s2 * D4 + c];
    float4 v3 = f4[(size_t)s3 * D4 + c];
    acc.x += g0 * v0.x + g1 * v1.x + g2 * v2.x + g3 * v3.x;
    acc.y += g0 * v0.y + g1 * v1.y + g2 * v2.y + g3 * v3.y;
    acc.z += g0 * v0.z + g1 * v1.z + g2 * v2.z + g3 * v3.z;
    acc.w += g0 * v0.w + g1 * v1.w + g2 * v2.w + g3 * v3.w;
  }
  for (; j < e; ++j) {
    int s = csr[j];
    float gs = norm[s];
    float4 v = f4[(size_t)s * D4 + c];
    acc.x += gs * v.x; acc.y += gs * v.y; acc.z += gs * v.z; acc.w += gs * v.w;
  }
  float gi = norm[i];
  float o0 = acc.x * gi, o1 = acc.y * gi, o2 = acc.z * gi, o3 = acc.w * gi;
  u16 h0 = f2bf(o0), h1 = f2bf(o1), h2 = f2bf(o2), h3 = f2bf(o3);
  ushort4 hv = make_ushort4(h0, h1, h2, h3);
  ushort4 lv = make_ushort4(f2bf(o0 - bf2f(h0)), f2bf(o1 - bf2f(h1)),
                            f2bf(o2 - bf2f(h2)), f2bf(o3 - bf2f(h3)));
  *(ushort4*)(XHi + (size_t)i * DD + c * 4) = hv;
  *(ushort4*)(XLo + (size_t)i * DD + c * 4) = lv;
}

// ---------------- W transpose + bf16 hi/lo split: Wt[si][col][k] ----------------

__global__ __launch_bounds__(256) void wsplit_kernel(
    const float* __restrict__ wh, const float* __restrict__ ws, const float* __restrict__ wm,
    u16* __restrict__ WtHi, u16* __restrict__ WtLo) {
  __shared__ float tile[64][65];
  int si = blockIdx.y;
  const float* W = (si == 0) ? wh : (si == 1) ? ws : wm;
  int tb = blockIdx.x;       // 0..63
  int kb = (tb >> 3) << 6;
  int cb = (tb & 7) << 6;
  int t = threadIdx.x;
#pragma unroll
  for (int i = 0; i < 16; ++i) {
    int idx = t + (i << 8);
    int kr = idx >> 6, cc = idx & 63;
    tile[kr][cc] = W[(size_t)(kb + kr) * DD + cb + cc];
  }
  __syncthreads();
  size_t base = (size_t)si * DD * DD;
#pragma unroll
  for (int i = 0; i < 16; ++i) {
    int idx = t + (i << 8);
    int cr = idx >> 6, kk = idx & 63;
    float v = tile[kk][cr];
    u16 hi = f2bf(v);
    u16 lo = f2bf(v - bf2f(hi));
    size_t off = base + (size_t)(cb + cr) * DD + kb + kk;
    WtHi[off] = hi;
    WtLo[off] = lo;
  }
}

// ---------------- fused 3-source split-bf16 MFMA GEMM + bias + relu ----------------
// out = relu([Xh|Xs|M] @ [Wh;Ws;Wm] + (bh+bs+bm)), via Ah*Bh + Al*Bh + Ah*Bl.
// Sources 0,1 (Xh,Xs): pre-split bf16 planes, staged via global_load_lds.
// Source 2 (M): fp32 input, reg-staged + split in-kernel.

#define BM 128
#define BN 256
#define BK 32

__global__ __launch_bounds__(256, 2) void gemm3_mfma(
    const u16* __restrict__ XhHi, const u16* __restrict__ XhLo,
    const u16* __restrict__ XsHi, const u16* __restrict__ XsLo,
    const float* __restrict__ Mm,
    const u16* __restrict__ WtHi, const u16* __restrict__ WtLo,
    const float* __restrict__ bh, const float* __restrict__ bs, const float* __restrict__ bm,
    float* __restrict__ out, int Mrows) {
  __shared__ u16 sAh[BM * BK];  // [row][k], 64B row stride
  __shared__ u16 sAl[BM * BK];
  __shared__ u16 sBh[BN * BK];  // [col][k]
  __shared__ u16 sBl[BN * BK];

  int tid = threadIdx.x;
  int wv = tid >> 6;
  int lane = tid & 63;
  int bm0 = blockIdx.y * BM;
  int bn0 = blockIdx.x * BN;

  f4v acc[8][4];
#pragma unroll
  for (int i = 0; i < 8; ++i)
#pragma unroll
    for (int j = 0; j < 4; ++j) acc[i][j] = (f4v){0.f, 0.f, 0.f, 0.f};

  for (int si = 0; si < 3; ++si) {
    const u16* AH = (si == 0) ? XhHi : XsHi;
    const u16* AL = (si == 0) ? XhLo : XsLo;
    const u16* WH = WtHi + (size_t)si * DD * DD;
    const u16* WL = WtLo + (size_t)si * DD * DD;
    for (int k0 = 0; k0 < DD; k0 += BK) {
      // --- B tile: async global->LDS (16 cols / instr) ---
      {
        int colo = lane >> 2;   // 0..15
        int chunk = lane & 3;   // 16B chunk = 8 k
#pragma unroll
        for (int i = 0; i < 4; ++i) {
          int cg = wv * 4 + i;  // col-group of 16
          int col = cg * 16 + colo;
          const u16* gh = WH + (size_t)(bn0 + col) * DD + k0 + chunk * 8;
          const u16* gl = WL + (size_t)(bn0 + col) * DD + k0 + chunk * 8;
          glds16(gh, (char*)sBh + cg * 1024);
          glds16(gl, (char*)sBl + cg * 1024);
        }
      }
      if (si < 2) {
        // --- A tile: async global->LDS from pre-split planes (16 rows / instr) ---
        int rowo = lane >> 2;
        int chunk = lane & 3;
#pragma unroll
        for (int i = 0; i < 2; ++i) {
          int rg = wv * 2 + i;  // row-group of 16
          int row = rg * 16 + rowo;
          const u16* gh = AH + (size_t)(bm0 + row) * DD + k0 + chunk * 8;
          const u16* gl = AL + (size_t)(bm0 + row) * DD + k0 + chunk * 8;
          glds16(gh, (char*)sAh + rg * 1024);
          glds16(gl, (char*)sAl + rg * 1024);
        }
      } else {
        // --- A tile: fp32 reg-stage, split to bf16 hi/lo, ds_write ---
        float4 vv[4];
#pragma unroll
        for (int i = 0; i < 4; ++i) {
          int idx = tid + (i << 8);
          int row = idx >> 3;
          int gr = bm0 + row;
          int kc = idx & 7;
          vv[i] = make_float4(0.f, 0.f, 0.f, 0.f);
          if (gr < Mrows) vv[i] = *(const float4*)(Mm + (size_t)gr * DD + k0 + kc * 4);
        }
#pragma unroll
        for (int i = 0; i < 4; ++i) {
          int idx = tid + (i << 8);
          int row = idx >> 3;
          int kc = idx & 7;
          float4 v = vv[i];
          u16 h0 = f2bf(v.x), h1 = f2bf(v.y), h2 = f2bf(v.z), h3 = f2bf(v.w);
          u16 l0 = f2bf(v.x - bf2f(h0)), l1 = f2bf(v.y - bf2f(h1));
          u16 l2 = f2bf(v.z - bf2f(h2)), l3 = f2bf(v.w - bf2f(h3));
          uint2 ph = make_uint2((u32)h0 | ((u32)h1 << 16), (u32)h2 | ((u32)h3 << 16));
          uint2 pl = make_uint2((u32)l0 | ((u32)l1 << 16), (u32)l2 | ((u32)l3 << 16));
          *(uint2*)(sAh + row * BK + kc * 4) = ph;
          *(uint2*)(sAl + row * BK + kc * 4) = pl;
        }
      }
      __syncthreads();
      // --- fragments + MFMA ---
      int kchunk = (lane >> 4) * 8;
      int rr = lane & 15;
      s8v bhf[4], blf[4];
#pragma unroll
      for (int ng = 0; ng < 4; ++ng) {
        int col = wv * 64 + ng * 16 + rr;
        bhf[ng] = *(const s8v*)(sBh + col * BK + kchunk);
        blf[ng] = *(const s8v*)(sBl + col * BK + kchunk);
      }
#pragma unroll
      for (int mg = 0; mg < 8; ++mg) {
        int row = mg * 16 + rr;
        s8v ah = *(const s8v*)(sAh + row * BK + kchunk);
        s8v al = *(const s8v*)(sAl + row * BK + kchunk);
#pragma unroll
        for (int ng = 0; ng < 4; ++ng) {
          acc[mg][ng] = __builtin_amdgcn_mfma_f32_16x16x32_bf16(ah, bhf[ng], acc[mg][ng], 0, 0, 0);
          acc[mg][ng] = __builtin_amdgcn_mfma_f32_16x16x32_bf16(al, bhf[ng], acc[mg][ng], 0, 0, 0);
          acc[mg][ng] = __builtin_amdgcn_mfma_f32_16x16x32_bf16(ah, blf[ng], acc[mg][ng], 0, 0, 0);
        }
      }
      __syncthreads();
    }
  }

  // --- epilogue: bias + relu, C/D layout col=lane&15, row=(lane>>4)*4+reg ---
  int rr = lane & 15;
  int rgrp = lane >> 4;
  float bias[4];
#pragma unroll
  for (int ng = 0; ng < 4; ++ng) {
    int col = bn0 + wv * 64 + ng * 16 + rr;
    bias[ng] = bh[col] + bs[col] + bm[col];
  }
#pragma unroll
  for (int mg = 0; mg < 8; ++mg) {
#pragma unroll
    for (int r = 0; r < 4; ++r) {
      int row = bm0 + mg * 16 + rgrp * 4 + r;
      if (row < Mrows) {
#pragma unroll
        for (int ng = 0; ng < 4; ++ng) {
          int col = bn0 + wv * 64 + ng * 16 + rr;
          float v = acc[mg][ng][r] + bias[ng];
          out[(size_t)row * DD + col] = v > 0.f ? v : 0.f;
        }
      }
    }
  }
}

// ---------------- launcher ----------------

extern "C" void kernel_launch(void* const* d_in, const int* in_sizes, int n_in,
                              void* d_out, int out_size, void* d_ws, size_t ws_size,
                              hipStream_t stream) {
  const float* h   = (const float*)d_in[0];
  const float* s   = (const float*)d_in[1];
  const float* m   = (const float*)d_in[2];
  const float* ng  = (const float*)d_in[3];
  const float* nf  = (const float*)d_in[4];
  const int* src_g = (const int*)d_in[5];
  const int* dst_g = (const int*)d_in[6];
  const int* src_f = (const int*)d_in[7];
  const int* dst_f = (const int*)d_in[8];
  const float* wh  = (const float*)d_in[9];
  const float* wsp = (const float*)d_in[10];
  const float* wm  = (const float*)d_in[11];
  const float* bh  = (const float*)d_in[12];
  const float* bs  = (const float*)d_in[13];
  const float* bm  = (const float*)d_in[14];
  float* out = (float*)d_out;

  int N = in_sizes[3];
  int E = in_sizes[5];
  int Npad = (N + BM - 1) & ~(BM - 1);  // rows padded to tile; pad rows never stored

  // workspace layout (16B-aligned segments)
  u16* XhHi = (u16*)d_ws;
  u16* XhLo = XhHi + (size_t)Npad * DD;
  u16* XsHi = XhLo + (size_t)Npad * DD;
  u16* XsLo = XsHi + (size_t)Npad * DD;
  u16* WtHi = XsLo + (size_t)Npad * DD;
  u16* WtLo = WtHi + (size_t)3 * DD * DD;
  int* deg_g = (int*)(WtLo + (size_t)3 * DD * DD);
  int* deg_f = deg_g + N;
  int* rp_g  = deg_f + N;
  int* rp_f  = rp_g + (N + 1);
  int* cur_g = rp_f + (N + 1);
  int* cur_f = cur_g + N;
  int* csr_g = cur_f + N;
  int* csr_f = csr_g + E;

  hipMemsetAsync(deg_g, 0, 2 * (size_t)N * sizeof(int), stream);
  wsplit_kernel<<<dim3(64, 3), 256, 0, stream>>>(wh, wsp, wm, WtHi, WtLo);
  hist_kernel<<<2048, 256, 0, stream>>>(dst_g, dst_f, deg_g, deg_f, E);
  scan_kernel<<<2, 256, 0, stream>>>(deg_g, deg_f, rp_g, rp_f, cur_g, cur_f, N);
  fill_kernel<<<2048, 256, 0, stream>>>(src_g, dst_g, cur_g, csr_g, E);
  fill_kernel<<<2048, 256, 0, stream>>>(src_f, dst_f, cur_f, csr_f, E);
  gather_kernel<<<N, 128, 0, stream>>>(h, ng, rp_g, csr_g, XhHi, XhLo, N);
  gather_kernel<<<N, 128, 0, stream>>>(s, nf, rp_f, csr_f, XsHi, XsLo, N);

  dim3 gg(DD / BN, (N + BM - 1) / BM);
  gemm3_mfma<<<gg, 256, 0, stream>>>(XhHi, XhLo, XsHi, XsLo, m, WtHi, WtLo,
                                     bh, bs, bm, out, N);
}

// Round 6
// 985.253 us; speedup vs baseline: 1.8058x; 1.1114x over previous
//
#include <hip/hip_runtime.h>
#include <hip/hip_bf16.h>
#include <cstdint>
#include <cstddef>

#define DD 512
#define D4 128

typedef unsigned short u16;
typedef unsigned int u32;
typedef short s8v __attribute__((ext_vector_type(8)));
typedef float f4v __attribute__((ext_vector_type(4)));

__device__ __forceinline__ u16 f2bf(float f) {
  u32 u = __builtin_bit_cast(u32, f);
  u = (u + 0x7FFFu + ((u >> 16) & 1u)) >> 16;  // RNE
  return (u16)u;
}
__device__ __forceinline__ float bf2f(u16 h) {
  u32 u = ((u32)h) << 16;
  return __builtin_bit_cast(float, u);
}

__device__ __forceinline__ void glds16(const void* g, void* l) {
  __builtin_amdgcn_global_load_lds(
      (const __attribute__((address_space(1))) void*)g,
      (__attribute__((address_space(3))) void*)l, 16, 0, 0);
}

// ---------------- CSR build ----------------

__global__ void hist_kernel(const int* __restrict__ dg, const int* __restrict__ df,
                            int* __restrict__ deg_g, int* __restrict__ deg_f, int E) {
  int i = blockIdx.x * blockDim.x + threadIdx.x;
  int total = 2 * E;
  int stride = gridDim.x * blockDim.x;
  for (; i < total; i += stride) {
    if (i < E) atomicAdd(&deg_g[dg[i]], 1);
    else       atomicAdd(&deg_f[df[i - E]], 1);
  }
}

__global__ void scan_kernel(const int* __restrict__ deg_g, const int* __restrict__ deg_f,
                            int* __restrict__ rp_g, int* __restrict__ rp_f,
                            int* __restrict__ cur_g, int* __restrict__ cur_f, int N) {
  const int* deg = (blockIdx.x == 0) ? deg_g : deg_f;
  int* rp  = (blockIdx.x == 0) ? rp_g  : rp_f;
  int* cur = (blockIdx.x == 0) ? cur_g : cur_f;
  __shared__ int sums[256];
  int t = threadIdx.x;
  int strip = (N + 255) / 256;
  int base = t * strip;
  int lim = N - base; if (lim > strip) lim = strip; if (lim < 0) lim = 0;
  int s = 0;
  for (int j = 0; j < lim; ++j) s += deg[base + j];
  sums[t] = s;
  __syncthreads();
  for (int off = 1; off < 256; off <<= 1) {
    int v = sums[t];
    int add = (t >= off) ? sums[t - off] : 0;
    __syncthreads();
    sums[t] = v + add;
    __syncthreads();
  }
  int run = (t == 0) ? 0 : sums[t - 1];
  for (int j = 0; j < lim; ++j) {
    rp[base + j] = run;
    cur[base + j] = run;
    run += deg[base + j];
  }
  if (t == 255) rp[N] = sums[255];
}

__global__ void fill_kernel(const int* __restrict__ src, const int* __restrict__ dst,
                            int* __restrict__ cur, int* __restrict__ csr, int E) {
  int i = blockIdx.x * blockDim.x + threadIdx.x;
  int stride = gridDim.x * blockDim.x;
  for (; i < E; i += stride) {
    int d = dst[i];
    int pos = atomicAdd(&cur[d], 1);
    csr[pos] = src[i];
  }
}

// ---------------- fp32 -> bf16 streaming convert ----------------

__global__ __launch_bounds__(256) void conv_bf16_kernel(const float* __restrict__ in,
                                                        u16* __restrict__ outb, int total4) {
  int i = blockIdx.x * blockDim.x + threadIdx.x;
  int stride = gridDim.x * blockDim.x;
  for (; i < total4; i += stride) {
    float4 v = ((const float4*)in)[i];
    ushort4 o = make_ushort4(f2bf(v.x), f2bf(v.y), f2bf(v.z), f2bf(v.w));
    ((ushort4*)outb)[i] = o;
  }
}

// ---------------- per-dst gather from bf16 rows; writes pre-split bf16 hi/lo ----------------
// X[i,:] = norm[i] * sum_{e: dst=i} norm[src_e] * featb[src_e,:]

__global__ __launch_bounds__(128) void gather_kernel(const u16* __restrict__ featb,
    const float* __restrict__ norm, const int* __restrict__ rp, const int* __restrict__ csr,
    u16* __restrict__ XHi, u16* __restrict__ XLo, int N) {
  int i = blockIdx.x;
  if (i >= N) return;
  int c = threadIdx.x;  // cols 4c..4c+3
  const ushort4* f8 = (const ushort4*)featb;  // row = 128 ushort4
  float a0 = 0.f, a1 = 0.f, a2 = 0.f, a3 = 0.f;
  int b = rp[i], e = rp[i + 1];
  int j = b;
  for (; j + 4 <= e; j += 4) {
    int s0 = csr[j], s1 = csr[j + 1], s2 = csr[j + 2], s3 = csr[j + 3];
    float g0 = norm[s0], g1 = norm[s1], g2 = norm[s2], g3 = norm[s3];
    ushort4 v0 = f8[(size_t)s0 * D4 + c];
    ushort4 v1 = f8[(size_t)s1 * D4 + c];
    ushort4 v2 = f8[(size_t)s2 * D4 + c];
    ushort4 v3 = f8[(size_t)s3 * D4 + c];
    a0 += g0 * bf2f(v0.x) + g1 * bf2f(v1.x) + g2 * bf2f(v2.x) + g3 * bf2f(v3.x);
    a1 += g0 * bf2f(v0.y) + g1 * bf2f(v1.y) + g2 * bf2f(v2.y) + g3 * bf2f(v3.y);
    a2 += g0 * bf2f(v0.z) + g1 * bf2f(v1.z) + g2 * bf2f(v2.z) + g3 * bf2f(v3.z);
    a3 += g0 * bf2f(v0.w) + g1 * bf2f(v1.w) + g2 * bf2f(v2.w) + g3 * bf2f(v3.w);
  }
  for (; j < e; ++j) {
    int s = csr[j];
    float gs = norm[s];
    ushort4 v = f8[(size_t)s * D4 + c];
    a0 += gs * bf2f(v.x); a1 += gs * bf2f(v.y); a2 += gs * bf2f(v.z); a3 += gs * bf2f(v.w);
  }
  float gi = norm[i];
  float o0 = a0 * gi, o1 = a1 * gi, o2 = a2 * gi, o3 = a3 * gi;
  u16 h0 = f2bf(o0), h1 = f2bf(o1), h2 = f2bf(o2), h3 = f2bf(o3);
  ushort4 hv = make_ushort4(h0, h1, h2, h3);
  ushort4 lv = make_ushort4(f2bf(o0 - bf2f(h0)), f2bf(o1 - bf2f(h1)),
                            f2bf(o2 - bf2f(h2)), f2bf(o3 - bf2f(h3)));
  *(ushort4*)(XHi + (size_t)i * DD + c * 4) = hv;
  *(ushort4*)(XLo + (size_t)i * DD + c * 4) = lv;
}

// ---------------- W transpose + bf16 hi/lo split: Wt[si][col][k] ----------------

__global__ __launch_bounds__(256) void wsplit_kernel(
    const float* __restrict__ wh, const float* __restrict__ ws, const float* __restrict__ wm,
    u16* __restrict__ WtHi, u16* __restrict__ WtLo) {
  __shared__ float tile[64][65];
  int si = blockIdx.y;
  const float* W = (si == 0) ? wh : (si == 1) ? ws : wm;
  int tb = blockIdx.x;       // 0..63
  int kb = (tb >> 3) << 6;
  int cb = (tb & 7) << 6;
  int t = threadIdx.x;
#pragma unroll
  for (int i = 0; i < 16; ++i) {
    int idx = t + (i << 8);
    int kr = idx >> 6, cc = idx & 63;
    tile[kr][cc] = W[(size_t)(kb + kr) * DD + cb + cc];
  }
  __syncthreads();
  size_t base = (size_t)si * DD * DD;
#pragma unroll
  for (int i = 0; i < 16; ++i) {
    int idx = t + (i << 8);
    int cr = idx >> 6, kk = idx & 63;
    float v = tile[kk][cr];
    u16 hi = f2bf(v);
    u16 lo = f2bf(v - bf2f(hi));
    size_t off = base + (size_t)(cb + cr) * DD + kb + kk;
    WtHi[off] = hi;
    WtLo[off] = lo;
  }
}

// ---------------- fused 3-source split-bf16 MFMA GEMM + bias + relu ----------------
// out = relu([Xh|Xs|M] @ [Wh;Ws;Wm] + (bh+bs+bm)), via Ah*Bh + Al*Bh + Ah*Bl.
// LDS chunk-XOR swizzle (chunk ^= (r>>1)&3) baked in via per-lane global source
// address for global_load_lds (LDS dest stays linear); matching XOR on frag reads.

#define BM 128
#define BN 256
#define BK 32

__global__ __launch_bounds__(256, 2) void gemm3_mfma(
    const u16* __restrict__ XhHi, const u16* __restrict__ XhLo,
    const u16* __restrict__ XsHi, const u16* __restrict__ XsLo,
    const float* __restrict__ Mm,
    const u16* __restrict__ WtHi, const u16* __restrict__ WtLo,
    const float* __restrict__ bh, const float* __restrict__ bs, const float* __restrict__ bm,
    float* __restrict__ out, int Mrows) {
  __shared__ u16 sAh[BM * BK];  // [row][chunk-swizzled k], 64B row stride
  __shared__ u16 sAl[BM * BK];
  __shared__ u16 sBh[BN * BK];  // [col][chunk-swizzled k]
  __shared__ u16 sBl[BN * BK];

  int tid = threadIdx.x;
  int wv = tid >> 6;
  int lane = tid & 63;
  int bm0 = blockIdx.y * BM;
  int bn0 = blockIdx.x * BN;

  f4v acc[8][4];
#pragma unroll
  for (int i = 0; i < 8; ++i)
#pragma unroll
    for (int j = 0; j < 4; ++j) acc[i][j] = (f4v){0.f, 0.f, 0.f, 0.f};

  for (int si = 0; si < 3; ++si) {
    const u16* AH = (si == 0) ? XhHi : XsHi;
    const u16* AL = (si == 0) ? XhLo : XsLo;
    const u16* WH = WtHi + (size_t)si * DD * DD;
    const u16* WL = WtLo + (size_t)si * DD * DD;
    for (int k0 = 0; k0 < DD; k0 += BK) {
      // --- B tile: async global->LDS, per-lane source chunk XOR ---
      {
        int colo = lane >> 2;   // 0..15
        int chunk = lane & 3;   // 16B chunk slot in LDS
#pragma unroll
        for (int i = 0; i < 4; ++i) {
          int cg = wv * 4 + i;
          int lcol = cg * 16 + colo;
          int sw = (lcol >> 1) & 3;
          const u16* gh = WH + (size_t)(bn0 + lcol) * DD + k0 + ((chunk ^ sw) * 8);
          const u16* gl = WL + (size_t)(bn0 + lcol) * DD + k0 + ((chunk ^ sw) * 8);
          glds16(gh, (char*)sBh + cg * 1024);
          glds16(gl, (char*)sBl + cg * 1024);
        }
      }
      if (si < 2) {
        // --- A tile: async global->LDS from pre-split planes, chunk XOR, row clamp ---
        int rowo = lane >> 2;
        int chunk = lane & 3;
#pragma unroll
        for (int i = 0; i < 2; ++i) {
          int rg = wv * 2 + i;
          int lrow = rg * 16 + rowo;
          int sw = (lrow >> 1) & 3;
          int grow = bm0 + lrow;
          if (grow >= Mrows) grow = Mrows - 1;  // tail clamp; rows >= Mrows never stored
          const u16* gh = AH + (size_t)grow * DD + k0 + ((chunk ^ sw) * 8);
          const u16* gl = AL + (size_t)grow * DD + k0 + ((chunk ^ sw) * 8);
          glds16(gh, (char*)sAh + rg * 1024);
          glds16(gl, (char*)sAl + rg * 1024);
        }
      } else {
        // --- A tile: fp32 reg-stage, split hi/lo, swizzled ds_write ---
        float4 vv[4];
#pragma unroll
        for (int i = 0; i < 4; ++i) {
          int idx = tid + (i << 8);
          int row = idx >> 3;
          int gr = bm0 + row;
          int kc = idx & 7;
          vv[i] = make_float4(0.f, 0.f, 0.f, 0.f);
          if (gr < Mrows) vv[i] = *(const float4*)(Mm + (size_t)gr * DD + k0 + kc * 4);
        }
#pragma unroll
        for (int i = 0; i < 4; ++i) {
          int idx = tid + (i << 8);
          int row = idx >> 3;
          int kc = idx & 7;       // 8B granule: logical chunk16 = kc>>1, half = kc&1
          int sw = (row >> 1) & 3;
          int off = row * 32 + (((kc >> 1) ^ sw) * 8) + (kc & 1) * 4;
          float4 v = vv[i];
          u16 h0 = f2bf(v.x), h1 = f2bf(v.y), h2 = f2bf(v.z), h3 = f2bf(v.w);
          u16 l0 = f2bf(v.x - bf2f(h0)), l1 = f2bf(v.y - bf2f(h1));
          u16 l2 = f2bf(v.z - bf2f(h2)), l3 = f2bf(v.w - bf2f(h3));
          uint2 ph = make_uint2((u32)h0 | ((u32)h1 << 16), (u32)h2 | ((u32)h3 << 16));
          uint2 pl = make_uint2((u32)l0 | ((u32)l1 << 16), (u32)l2 | ((u32)l3 << 16));
          *(uint2*)(sAh + off) = ph;
          *(uint2*)(sAl + off) = pl;
        }
      }
      __syncthreads();
      // --- fragments + MFMA (XOR-swizzled reads) ---
      int c16 = lane >> 4;      // logical 16B chunk 0..3
      int rr = lane & 15;
      s8v bhf[4], blf[4];
#pragma unroll
      for (int ng = 0; ng < 4; ++ng) {
        int col = wv * 64 + ng * 16 + rr;
        int sw = (col >> 1) & 3;
        bhf[ng] = *(const s8v*)(sBh + col * 32 + ((c16 ^ sw) * 8));
        blf[ng] = *(const s8v*)(sBl + col * 32 + ((c16 ^ sw) * 8));
      }
#pragma unroll
      for (int mg = 0; mg < 8; ++mg) {
        int row = mg * 16 + rr;
        int sw = (row >> 1) & 3;
        s8v ah = *(const s8v*)(sAh + row * 32 + ((c16 ^ sw) * 8));
        s8v al = *(const s8v*)(sAl + row * 32 + ((c16 ^ sw) * 8));
#pragma unroll
        for (int ng = 0; ng < 4; ++ng) {
          acc[mg][ng] = __builtin_amdgcn_mfma_f32_16x16x32_bf16(ah, bhf[ng], acc[mg][ng], 0, 0, 0);
          acc[mg][ng] = __builtin_amdgcn_mfma_f32_16x16x32_bf16(al, bhf[ng], acc[mg][ng], 0, 0, 0);
          acc[mg][ng] = __builtin_amdgcn_mfma_f32_16x16x32_bf16(ah, blf[ng], acc[mg][ng], 0, 0, 0);
        }
      }
      __syncthreads();
    }
  }

  // --- epilogue: bias + relu, C/D layout col=lane&15, row=(lane>>4)*4+reg ---
  int rr = lane & 15;
  int rgrp = lane >> 4;
  float bias[4];
#pragma unroll
  for (int ng = 0; ng < 4; ++ng) {
    int col = bn0 + wv * 64 + ng * 16 + rr;
    bias[ng] = bh[col] + bs[col] + bm[col];
  }
#pragma unroll
  for (int mg = 0; mg < 8; ++mg) {
#pragma unroll
    for (int r = 0; r < 4; ++r) {
      int row = bm0 + mg * 16 + rgrp * 4 + r;
      if (row < Mrows) {
#pragma unroll
        for (int ng = 0; ng < 4; ++ng) {
          int col = bn0 + wv * 64 + ng * 16 + rr;
          float v = acc[mg][ng][r] + bias[ng];
          out[(size_t)row * DD + col] = v > 0.f ? v : 0.f;
        }
      }
    }
  }
}

// ---------------- launcher ----------------

extern "C" void kernel_launch(void* const* d_in, const int* in_sizes, int n_in,
                              void* d_out, int out_size, void* d_ws, size_t ws_size,
                              hipStream_t stream) {
  const float* h   = (const float*)d_in[0];
  const float* s   = (const float*)d_in[1];
  const float* m   = (const float*)d_in[2];
  const float* ng  = (const float*)d_in[3];
  const float* nf  = (const float*)d_in[4];
  const int* src_g = (const int*)d_in[5];
  const int* dst_g = (const int*)d_in[6];
  const int* src_f = (const int*)d_in[7];
  const int* dst_f = (const int*)d_in[8];
  const float* wh  = (const float*)d_in[9];
  const float* wsp = (const float*)d_in[10];
  const float* wm  = (const float*)d_in[11];
  const float* bh  = (const float*)d_in[12];
  const float* bs  = (const float*)d_in[13];
  const float* bm  = (const float*)d_in[14];
  float* out = (float*)d_out;

  int N = in_sizes[3];
  int E = in_sizes[5];

  // workspace layout (16B-aligned segments), total ~265 MB
  u16* XhHi = (u16*)d_ws;
  u16* XhLo = XhHi + (size_t)N * DD;
  u16* XsHi = XhLo + (size_t)N * DD;
  u16* XsLo = XsHi + (size_t)N * DD;
  u16* featb = XsLo + (size_t)N * DD;           // shared h/s bf16 buffer
  u16* WtHi = featb + (size_t)N * DD;
  u16* WtLo = WtHi + (size_t)3 * DD * DD;
  int* deg_g = (int*)(WtLo + (size_t)3 * DD * DD);
  int* deg_f = deg_g + N;
  int* rp_g  = deg_f + N;
  int* rp_f  = rp_g + (N + 1);
  int* cur_g = rp_f + (N + 1);
  int* cur_f = cur_g + N;
  int* csr_g = cur_f + N;
  int* csr_f = csr_g + E;

  int total4 = (N * DD) / 4;

  hipMemsetAsync(deg_g, 0, 2 * (size_t)N * sizeof(int), stream);
  wsplit_kernel<<<dim3(64, 3), 256, 0, stream>>>(wh, wsp, wm, WtHi, WtLo);
  hist_kernel<<<2048, 256, 0, stream>>>(dst_g, dst_f, deg_g, deg_f, E);
  scan_kernel<<<2, 256, 0, stream>>>(deg_g, deg_f, rp_g, rp_f, cur_g, cur_f, N);
  fill_kernel<<<2048, 256, 0, stream>>>(src_g, dst_g, cur_g, csr_g, E);
  fill_kernel<<<2048, 256, 0, stream>>>(src_f, dst_f, cur_f, csr_f, E);
  conv_bf16_kernel<<<2048, 256, 0, stream>>>(h, featb, total4);
  gather_kernel<<<N, 128, 0, stream>>>(featb, ng, rp_g, csr_g, XhHi, XhLo, N);
  conv_bf16_kernel<<<2048, 256, 0, stream>>>(s, featb, total4);
  gather_kernel<<<N, 128, 0, stream>>>(featb, nf, rp_f, csr_f, XsHi, XsLo, N);

  dim3 gg(DD / BN, (N + BM - 1) / BM);
  gemm3_mfma<<<gg, 256, 0, stream>>>(XhHi, XhLo, XsHi, XsLo, m, WtHi, WtLo,
                                     bh, bs, bm, out, N);
}

// Round 8
// 956.196 us; speedup vs baseline: 1.8607x; 1.0304x over previous
//
#include <hip/hip_runtime.h>
#include <hip/hip_bf16.h>
#include <cstdint>
#include <cstddef>

#define DD 512
#define D4 128

typedef unsigned short u16;
typedef unsigned int u32;
typedef short s8v __attribute__((ext_vector_type(8)));
typedef float f4v __attribute__((ext_vector_type(4)));
typedef u16 u16v8 __attribute__((ext_vector_type(8)));

__device__ __forceinline__ u16 f2bf(float f) {
  u32 u = __builtin_bit_cast(u32, f);
  u = (u + 0x7FFFu + ((u >> 16) & 1u)) >> 16;  // RNE
  return (u16)u;
}
__device__ __forceinline__ float bf2f(u16 h) {
  u32 u = ((u32)h) << 16;
  return __builtin_bit_cast(float, u);
}

__device__ __forceinline__ void glds16(const void* g, void* l) {
  __builtin_amdgcn_global_load_lds(
      (const __attribute__((address_space(1))) void*)g,
      (__attribute__((address_space(3))) void*)l, 16, 0, 0);
}

// ---------------- CSR build ----------------

__global__ void hist_kernel(const int* __restrict__ dg, const int* __restrict__ df,
                            int* __restrict__ deg_g, int* __restrict__ deg_f, int E) {
  int i = blockIdx.x * blockDim.x + threadIdx.x;
  int total = 2 * E;
  int stride = gridDim.x * blockDim.x;
  for (; i < total; i += stride) {
    if (i < E) atomicAdd(&deg_g[dg[i]], 1);
    else       atomicAdd(&deg_f[df[i - E]], 1);
  }
}

__global__ void scan_kernel(const int* __restrict__ deg_g, const int* __restrict__ deg_f,
                            int* __restrict__ rp_g, int* __restrict__ rp_f,
                            int* __restrict__ cur_g, int* __restrict__ cur_f, int N) {
  const int* deg = (blockIdx.x == 0) ? deg_g : deg_f;
  int* rp  = (blockIdx.x == 0) ? rp_g  : rp_f;
  int* cur = (blockIdx.x == 0) ? cur_g : cur_f;
  __shared__ int sums[256];
  int t = threadIdx.x;
  int strip = (N + 255) / 256;
  int base = t * strip;
  int lim = N - base; if (lim > strip) lim = strip; if (lim < 0) lim = 0;
  int s = 0;
  for (int j = 0; j < lim; ++j) s += deg[base + j];
  sums[t] = s;
  __syncthreads();
  for (int off = 1; off < 256; off <<= 1) {
    int v = sums[t];
    int add = (t >= off) ? sums[t - off] : 0;
    __syncthreads();
    sums[t] = v + add;
    __syncthreads();
  }
  int run = (t == 0) ? 0 : sums[t - 1];
  for (int j = 0; j < lim; ++j) {
    rp[base + j] = run;
    cur[base + j] = run;
    run += deg[base + j];
  }
  if (t == 255) rp[N] = sums[255];
}

__global__ void fill_kernel(const int* __restrict__ src, const int* __restrict__ dst,
                            int* __restrict__ cur, int* __restrict__ csr, int E) {
  int i = blockIdx.x * blockDim.x + threadIdx.x;
  int stride = gridDim.x * blockDim.x;
  for (; i < E; i += stride) {
    int d = dst[i];
    int pos = atomicAdd(&cur[d], 1);
    csr[pos] = src[i];
  }
}

// ---------------- fp32 -> bf16 streaming convert (hi only) ----------------

__global__ __launch_bounds__(256) void conv_bf16_kernel(const float* __restrict__ in,
                                                        u16* __restrict__ outb, int total4) {
  int i = blockIdx.x * blockDim.x + threadIdx.x;
  int stride = gridDim.x * blockDim.x;
  for (; i < total4; i += stride) {
    float4 v = ((const float4*)in)[i];
    ushort4 o = make_ushort4(f2bf(v.x), f2bf(v.y), f2bf(v.z), f2bf(v.w));
    ((ushort4*)outb)[i] = o;
  }
}

// ---------------- fp32 -> bf16 hi/lo split convert (for M) ----------------

__global__ __launch_bounds__(256) void convsplit_kernel(const float* __restrict__ in,
                                                        u16* __restrict__ hi, u16* __restrict__ lo,
                                                        int total4) {
  int i = blockIdx.x * blockDim.x + threadIdx.x;
  int stride = gridDim.x * blockDim.x;
  for (; i < total4; i += stride) {
    float4 v = ((const float4*)in)[i];
    u16 h0 = f2bf(v.x), h1 = f2bf(v.y), h2 = f2bf(v.z), h3 = f2bf(v.w);
    ((ushort4*)hi)[i] = make_ushort4(h0, h1, h2, h3);
    ((ushort4*)lo)[i] = make_ushort4(f2bf(v.x - bf2f(h0)), f2bf(v.y - bf2f(h1)),
                                     f2bf(v.z - bf2f(h2)), f2bf(v.w - bf2f(h3)));
  }
}

// ---------------- per-dst gather: one wave per node, 16B row loads ----------------
// X[i,:] = norm[i] * sum_{e: dst=i} norm[src_e] * featb[src_e,:]

__global__ __launch_bounds__(256) void gather_kernel(const u16* __restrict__ featb,
    const float* __restrict__ norm, const int* __restrict__ rp, const int* __restrict__ csr,
    u16* __restrict__ XHi, u16* __restrict__ XLo, int N) {
  int w = threadIdx.x >> 6;
  int lane = threadIdx.x & 63;
  int i = blockIdx.x * 4 + w;
  if (i >= N) return;
  const u16v8* f8 = (const u16v8*)featb;  // row = 64 x u16v8
  float a[8];
#pragma unroll
  for (int t = 0; t < 8; ++t) a[t] = 0.f;
  int b = rp[i], e = rp[i + 1];
  int j = b;
  for (; j + 4 <= e; j += 4) {
    int s0 = csr[j], s1 = csr[j + 1], s2 = csr[j + 2], s3 = csr[j + 3];
    float g0 = norm[s0], g1 = norm[s1], g2 = norm[s2], g3 = norm[s3];
    u16v8 v0 = f8[(size_t)s0 * 64 + lane];
    u16v8 v1 = f8[(size_t)s1 * 64 + lane];
    u16v8 v2 = f8[(size_t)s2 * 64 + lane];
    u16v8 v3 = f8[(size_t)s3 * 64 + lane];
#pragma unroll
    for (int t = 0; t < 8; ++t)
      a[t] += g0 * bf2f(v0[t]) + g1 * bf2f(v1[t]) + g2 * bf2f(v2[t]) + g3 * bf2f(v3[t]);
  }
  for (; j < e; ++j) {
    int s = csr[j];
    float gs = norm[s];
    u16v8 v = f8[(size_t)s * 64 + lane];
#pragma unroll
    for (int t = 0; t < 8; ++t) a[t] += gs * bf2f(v[t]);
  }
  float gi = norm[i];
  u16v8 hv, lv;
#pragma unroll
  for (int t = 0; t < 8; ++t) {
    float o = a[t] * gi;
    u16 hh = f2bf(o);
    hv[t] = hh;
    lv[t] = f2bf(o - bf2f(hh));
  }
  *(u16v8*)(XHi + (size_t)i * DD + lane * 8) = hv;
  *(u16v8*)(XLo + (size_t)i * DD + lane * 8) = lv;
}

// ---------------- W transpose + bf16 hi/lo split: Wt[si][col][k] ----------------

__global__ __launch_bounds__(256) void wsplit_kernel(
    const float* __restrict__ wh, const float* __restrict__ ws, const float* __restrict__ wm,
    u16* __restrict__ WtHi, u16* __restrict__ WtLo) {
  __shared__ float tile[64][65];
  int si = blockIdx.y;
  const float* W = (si == 0) ? wh : (si == 1) ? ws : wm;
  int tb = blockIdx.x;       // 0..63
  int kb = (tb >> 3) << 6;
  int cb = (tb & 7) << 6;
  int t = threadIdx.x;
#pragma unroll
  for (int i = 0; i < 16; ++i) {
    int idx = t + (i << 8);
    int kr = idx >> 6, cc = idx & 63;
    tile[kr][cc] = W[(size_t)(kb + kr) * DD + cb + cc];
  }
  __syncthreads();
  size_t base = (size_t)si * DD * DD;
#pragma unroll
  for (int i = 0; i < 16; ++i) {
    int idx = t + (i << 8);
    int cr = idx >> 6, kk = idx & 63;
    float v = tile[kk][cr];
    u16 hi = f2bf(v);
    u16 lo = f2bf(v - bf2f(hi));
    size_t off = base + (size_t)(cb + cr) * DD + kb + kk;
    WtHi[off] = hi;
    WtLo[off] = lo;
  }
}

// ---------------- fused 3-source split-bf16 MFMA GEMM + bias + relu ----------------
// out = relu([Xh|Xs|M] @ [Wh;Ws;Wm] + (bh+bs+bm)), via Ah*Bh + Al*Bh + Ah*Bl.
// All A sources pre-split bf16 planes -> uniform global_load_lds staging.
// Chunk-XOR LDS swizzle (verified: 0 bank conflicts) + bijective XCD block swizzle.

#define BM 128
#define BN 256
#define BK 32

__global__ __launch_bounds__(256, 2) void gemm3_mfma(
    const u16* __restrict__ XhHi, const u16* __restrict__ XhLo,
    const u16* __restrict__ XsHi, const u16* __restrict__ XsLo,
    const u16* __restrict__ MHi,  const u16* __restrict__ MLo,
    const u16* __restrict__ WtHi, const u16* __restrict__ WtLo,
    const float* __restrict__ bh, const float* __restrict__ bs, const float* __restrict__ bm,
    float* __restrict__ out, int Mrows) {
  __shared__ u16 sAh[BM * BK];  // [row][chunk-swizzled k], 64B row stride
  __shared__ u16 sAl[BM * BK];
  __shared__ u16 sBh[BN * BK];  // [col][chunk-swizzled k]
  __shared__ u16 sBl[BN * BK];

  int tid = threadIdx.x;
  int wv = tid >> 6;
  int lane = tid & 63;

  // bijective XCD swizzle (m204): chunk the flat grid so adjacent col-pairs
  // (which share a 786KB A-panel) land on the same XCD's L2.
  int nwg = gridDim.x;
  int orig = blockIdx.x;
  int q = nwg >> 3, r = nwg & 7;
  int xcd = orig & 7, pos = orig >> 3;
  int sid = (xcd < r ? xcd * (q + 1) : r * (q + 1) + (xcd - r) * q) + pos;
  int bn0 = (sid & 1) * BN;       // 2 col-blocks (DD/BN)
  int bm0 = (sid >> 1) * BM;

  f4v acc[8][4];
#pragma unroll
  for (int i = 0; i < 8; ++i)
#pragma unroll
    for (int j = 0; j < 4; ++j) acc[i][j] = (f4v){0.f, 0.f, 0.f, 0.f};

  for (int si = 0; si < 3; ++si) {
    const u16* AH = (si == 0) ? XhHi : (si == 1) ? XsHi : MHi;
    const u16* AL = (si == 0) ? XhLo : (si == 1) ? XsLo : MLo;
    const u16* WH = WtHi + (size_t)si * DD * DD;
    const u16* WL = WtLo + (size_t)si * DD * DD;
    for (int k0 = 0; k0 < DD; k0 += BK) {
      // --- B tile: async global->LDS, per-lane source chunk XOR ---
      {
        int colo = lane >> 2;   // 0..15
        int chunk = lane & 3;   // 16B chunk slot in LDS
#pragma unroll
        for (int i = 0; i < 4; ++i) {
          int cg = wv * 4 + i;
          int lcol = cg * 16 + colo;
          int sw = (lcol >> 1) & 3;
          const u16* gh = WH + (size_t)(bn0 + lcol) * DD + k0 + ((chunk ^ sw) * 8);
          const u16* gl = WL + (size_t)(bn0 + lcol) * DD + k0 + ((chunk ^ sw) * 8);
          glds16(gh, (char*)sBh + cg * 1024);
          glds16(gl, (char*)sBl + cg * 1024);
        }
      }
      // --- A tile: async global->LDS from pre-split planes, chunk XOR, row clamp ---
      {
        int rowo = lane >> 2;
        int chunk = lane & 3;
#pragma unroll
        for (int i = 0; i < 2; ++i) {
          int rg = wv * 2 + i;
          int lrow = rg * 16 + rowo;
          int sw = (lrow >> 1) & 3;
          int grow = bm0 + lrow;
          if (grow >= Mrows) grow = Mrows - 1;  // tail clamp; rows >= Mrows never stored
          const u16* gh = AH + (size_t)grow * DD + k0 + ((chunk ^ sw) * 8);
          const u16* gl = AL + (size_t)grow * DD + k0 + ((chunk ^ sw) * 8);
          glds16(gh, (char*)sAh + rg * 1024);
          glds16(gl, (char*)sAl + rg * 1024);
        }
      }
      __syncthreads();
      // --- fragments + MFMA (XOR-swizzled reads) ---
      int c16 = lane >> 4;      // logical 16B chunk 0..3
      int rr = lane & 15;
      s8v bhf[4], blf[4];
#pragma unroll
      for (int ng = 0; ng < 4; ++ng) {
        int col = wv * 64 + ng * 16 + rr;
        int sw = (col >> 1) & 3;
        bhf[ng] = *(const s8v*)(sBh + col * 32 + ((c16 ^ sw) * 8));
        blf[ng] = *(const s8v*)(sBl + col * 32 + ((c16 ^ sw) * 8));
      }
#pragma unroll
      for (int mg = 0; mg < 8; ++mg) {
        int row = mg * 16 + rr;
        int sw = (row >> 1) & 3;
        s8v ah = *(const s8v*)(sAh + row * 32 + ((c16 ^ sw) * 8));
        s8v al = *(const s8v*)(sAl + row * 32 + ((c16 ^ sw) * 8));
#pragma unroll
        for (int ng = 0; ng < 4; ++ng) {
          acc[mg][ng] = __builtin_amdgcn_mfma_f32_16x16x32_bf16(ah, bhf[ng], acc[mg][ng], 0, 0, 0);
          acc[mg][ng] = __builtin_amdgcn_mfma_f32_16x16x32_bf16(al, bhf[ng], acc[mg][ng], 0, 0, 0);
          acc[mg][ng] = __builtin_amdgcn_mfma_f32_16x16x32_bf16(ah, blf[ng], acc[mg][ng], 0, 0, 0);
        }
      }
      __syncthreads();
    }
  }

  // --- epilogue: bias + relu, C/D layout col=lane&15, row=(lane>>4)*4+reg ---
  int rr = lane & 15;
  int rgrp = lane >> 4;
  float bias[4];
#pragma unroll
  for (int ng = 0; ng < 4; ++ng) {
    int col = bn0 + wv * 64 + ng * 16 + rr;
    bias[ng] = bh[col] + bs[col] + bm[col];
  }
#pragma unroll
  for (int mg = 0; mg < 8; ++mg) {
#pragma unroll
    for (int r = 0; r < 4; ++r) {
      int row = bm0 + mg * 16 + rgrp * 4 + r;
      if (row < Mrows) {
#pragma unroll
        for (int ng = 0; ng < 4; ++ng) {
          int col = bn0 + wv * 64 + ng * 16 + rr;
          float v = acc[mg][ng][r] + bias[ng];
          out[(size_t)row * DD + col] = v > 0.f ? v : 0.f;
        }
      }
    }
  }
}

// ---------------- launcher ----------------

extern "C" void kernel_launch(void* const* d_in, const int* in_sizes, int n_in,
                              void* d_out, int out_size, void* d_ws, size_t ws_size,
                              hipStream_t stream) {
  const float* h   = (const float*)d_in[0];
  const float* s   = (const float*)d_in[1];
  const float* m   = (const float*)d_in[2];
  const float* ng  = (const float*)d_in[3];
  const float* nf  = (const float*)d_in[4];
  const int* src_g = (const int*)d_in[5];
  const int* dst_g = (const int*)d_in[6];
  const int* src_f = (const int*)d_in[7];
  const int* dst_f = (const int*)d_in[8];
  const float* wh  = (const float*)d_in[9];
  const float* wsp = (const float*)d_in[10];
  const float* wm  = (const float*)d_in[11];
  const float* bh  = (const float*)d_in[12];
  const float* bs  = (const float*)d_in[13];
  const float* bm  = (const float*)d_in[14];
  float* out = (float*)d_out;

  int N = in_sizes[3];
  int E = in_sizes[5];

  // workspace layout (16B-aligned segments), ~319 MB.
  // MHi slot doubles as the transient bf16 feature buffer (featb) for the
  // gathers: conv(h)->featb, gather(h); conv(s)->featb, gather(s);
  // convsplit(m)->(MHi=featb, MLo); gemm.
  u16* XhHi = (u16*)d_ws;
  u16* XhLo = XhHi + (size_t)N * DD;
  u16* XsHi = XhLo + (size_t)N * DD;
  u16* XsLo = XsHi + (size_t)N * DD;
  u16* MHi  = XsLo + (size_t)N * DD;   // == featb
  u16* MLo  = MHi + (size_t)N * DD;
  u16* featb = MHi;
  u16* WtHi = MLo + (size_t)N * DD;
  u16* WtLo = WtHi + (size_t)3 * DD * DD;
  int* deg_g = (int*)(WtLo + (size_t)3 * DD * DD);
  int* deg_f = deg_g + N;
  int* rp_g  = deg_f + N;
  int* rp_f  = rp_g + (N + 1);
  int* cur_g = rp_f + (N + 1);
  int* cur_f = cur_g + N;
  int* csr_g = cur_f + N;
  int* csr_f = csr_g + E;

  int total4 = (N * DD) / 4;

  hipMemsetAsync(deg_g, 0, 2 * (size_t)N * sizeof(int), stream);
  wsplit_kernel<<<dim3(64, 3), 256, 0, stream>>>(wh, wsp, wm, WtHi, WtLo);
  hist_kernel<<<2048, 256, 0, stream>>>(dst_g, dst_f, deg_g, deg_f, E);
  scan_kernel<<<2, 256, 0, stream>>>(deg_g, deg_f, rp_g, rp_f, cur_g, cur_f, N);
  fill_kernel<<<2048, 256, 0, stream>>>(src_g, dst_g, cur_g, csr_g, E);
  fill_kernel<<<2048, 256, 0, stream>>>(src_f, dst_f, cur_f, csr_f, E);
  conv_bf16_kernel<<<2048, 256, 0, stream>>>(h, featb, total4);
  gather_kernel<<<(N + 3) / 4, 256, 0, stream>>>(featb, ng, rp_g, csr_g, XhHi, XhLo, N);
  conv_bf16_kernel<<<2048, 256, 0, stream>>>(s, featb, total4);
  gather_kernel<<<(N + 3) / 4, 256, 0, stream>>>(featb, nf, rp_f, csr_f, XsHi, XsLo, N);
  convsplit_kernel<<<2048, 256, 0, stream>>>(m, MHi, MLo, total4);

  int nrb = (N + BM - 1) / BM;
  int nwg = (DD / BN) * nrb;
  gemm3_mfma<<<nwg, 256, 0, stream>>>(XhHi, XhLo, XsHi, XsLo, MHi, MLo, WtHi, WtLo,
                                      bh, bs, bm, out, N);
}